// Round 1
// baseline (269.699 us; speedup 1.0000x reference)
//
#include <hip/hip_runtime.h>

// Integrate-and-fire forward: x (T=32, B=16, N=65536) fp32 -> y same shape.
// Per neuron: m = v + x[t]; y = (m >= 1) ? 1 : 0; v = m - y.
// Parallel over B*N neurons; T-loop in registers. Memory-bound (256 MiB traffic).

#define T_STEPS 32

__global__ __launch_bounds__(256) void if_fwd_kernel(const float4* __restrict__ x,
                                                     float4* __restrict__ y,
                                                     int bn4) {
    const int i = blockIdx.x * blockDim.x + threadIdx.x;
    if (i >= bn4) return;

    float4 v = make_float4(0.f, 0.f, 0.f, 0.f);

#pragma unroll
    for (int t = 0; t < T_STEPS; ++t) {
        const size_t off = (size_t)t * (size_t)bn4 + (size_t)i;
        float4 xt = x[off];

        float4 m;
        m.x = v.x + xt.x;
        m.y = v.y + xt.y;
        m.z = v.z + xt.z;
        m.w = v.w + xt.w;

        float4 s;
        s.x = (m.x >= 1.0f) ? 1.0f : 0.0f;
        s.y = (m.y >= 1.0f) ? 1.0f : 0.0f;
        s.z = (m.z >= 1.0f) ? 1.0f : 0.0f;
        s.w = (m.w >= 1.0f) ? 1.0f : 0.0f;

        v.x = m.x - s.x;
        v.y = m.y - s.y;
        v.z = m.z - s.z;
        v.w = m.w - s.w;

        y[off] = s;
    }
}

extern "C" void kernel_launch(void* const* d_in, const int* in_sizes, int n_in,
                              void* d_out, int out_size, void* d_ws, size_t ws_size,
                              hipStream_t stream) {
    const float* x = (const float*)d_in[0];
    float* y = (float*)d_out;

    // in_sizes[0] = T*B*N; neurons = B*N = total / T
    const int total = in_sizes[0];
    const int bn = total / T_STEPS;   // 1,048,576
    const int bn4 = bn / 4;           // 262,144 float4 lanes

    const int block = 256;
    const int grid = (bn4 + block - 1) / block;  // 1024

    if_fwd_kernel<<<grid, block, 0, stream>>>((const float4*)x, (float4*)y, bn4);
}

// Round 8
// 223.838 us; speedup vs baseline: 1.2049x; 1.2049x over previous
//
#include <hip/hip_runtime.h>

// Integrate-and-fire forward: x (T=32, B=16, N=65536) fp32 -> y same shape.
// Per neuron: m = v + x[t]; y = (m >= 1) ? 1 : 0; v = m - y  (soft reset).
// Parallel over B*N neurons; sequential T-loop in registers.
// Memory-bound streaming: 256 MiB total traffic, target ~6.3 TB/s.
//
// vs round-1 (latency-bound at 28% HBM, Occupancy 26%, VALUBusy 2.3%):
//  - 2 floats/thread: 2x threads -> 2048 WGs = 8 WG/CU = 32 waves/CU
//  - explicit 4-deep register prefetch (statically indexed, fully unrolled)
//  - nontemporal loads/stores: both streams are touch-once, keep L2 clean
//  - NOTE: __builtin_nontemporal_* needs clang ext_vector_type, not HIP float2
//    (HIP_vector_type is a class -> compile error, round-6 lesson)

#define T_STEPS 32
#define PF 4  // prefetch depth (outstanding loads per wave)

typedef float f32x2 __attribute__((ext_vector_type(2)));

__global__ __launch_bounds__(256) void if_fwd_kernel(const f32x2* __restrict__ x,
                                                     f32x2* __restrict__ y,
                                                     int bn2) {
    const int i = blockIdx.x * blockDim.x + threadIdx.x;
    if (i >= bn2) return;

    // Prime the pipeline: PF loads in flight before any compute.
    f32x2 buf[PF];
#pragma unroll
    for (int t = 0; t < PF; ++t)
        buf[t] = __builtin_nontemporal_load(&x[(size_t)t * (size_t)bn2 + (size_t)i]);

    float vx = 0.f, vy = 0.f;

#pragma unroll
    for (int t = 0; t < T_STEPS; ++t) {
        f32x2 xt = buf[t % PF];  // compile-time index after full unroll

        // Issue the t+PF load before consuming t: keeps PF loads outstanding.
        if (t + PF < T_STEPS)
            buf[(t + PF) % PF] =
                __builtin_nontemporal_load(&x[(size_t)(t + PF) * (size_t)bn2 + (size_t)i]);

        float mx = vx + xt.x;
        float my = vy + xt.y;
        float sx = (mx >= 1.0f) ? 1.0f : 0.0f;
        float sy = (my >= 1.0f) ? 1.0f : 0.0f;
        vx = mx - sx;
        vy = my - sy;

        f32x2 s;
        s.x = sx;
        s.y = sy;
        __builtin_nontemporal_store(s, &y[(size_t)t * (size_t)bn2 + (size_t)i]);
    }
}

extern "C" void kernel_launch(void* const* d_in, const int* in_sizes, int n_in,
                              void* d_out, int out_size, void* d_ws, size_t ws_size,
                              hipStream_t stream) {
    const float* x = (const float*)d_in[0];
    float* y = (float*)d_out;

    const int total = in_sizes[0];      // T*B*N
    const int bn = total / T_STEPS;     // 1,048,576 neurons
    const int bn2 = bn / 2;             // 524,288 f32x2 lanes

    const int block = 256;
    const int grid = (bn2 + block - 1) / block;  // 2048 WGs -> 8 WG/CU

    if_fwd_kernel<<<grid, block, 0, stream>>>((const f32x2*)x, (f32x2*)y, bn2);
}